// Round 10
// baseline (226.712 us; speedup 1.0000x reference)
//
#include <hip/hip_runtime.h>
#include <stdint.h>

// ---------- helpers ----------
typedef __attribute__((ext_vector_type(8))) short bf16x8;          // 8 bf16
typedef __attribute__((ext_vector_type(8))) unsigned short u16x8;  // 8 u16
typedef __attribute__((ext_vector_type(4))) float f32x4;

__device__ __forceinline__ float bf2f(uint16_t h) { return __uint_as_float(((uint32_t)h) << 16); }
__device__ __forceinline__ uint16_t f2bf(float f) {  // RNE, finite inputs only
  uint32_t u = __float_as_uint(f);
  u += 0x7fffu + ((u >> 16) & 1u);
  return (uint16_t)(u >> 16);
}

#define NSHADOW 64

// ---------- prep: weights f32 -> bf16 fragment-order; biases/gamma/beta f32;
// zero shadow. Grid: 48 x 256 = 12288 threads.
// Fragment order: chunk c=(tile tt, kstep kk), lane l=(quad q, m):
// 8 elems W[kk*32+q*8+j][tt*16+m] contiguous at D + (c*64+l)*8.
__global__ __launch_bounds__(256) void prep_k(
    const float* __restrict__ W1, const float* __restrict__ Wf1,
    const float* __restrict__ W2, const float* __restrict__ Wf2,
    const float* __restrict__ b1, const float* __restrict__ bf1,
    const float* __restrict__ b2, const float* __restrict__ bf2,
    const float* __restrict__ gam, const float* __restrict__ bet,
    uint16_t* __restrict__ F1, uint16_t* __restrict__ Ff1,
    uint16_t* __restrict__ F2, uint16_t* __restrict__ Ff2,
    float* __restrict__ fb, float* __restrict__ fgb,
    float* __restrict__ shadow)
{
  int t = blockIdx.x * 256 + threadIdx.x;   // 0..12287
  for (int i = t; i < NSHADOW * 256; i += 12288) shadow[i] = 0.f;
  {
    const float* W; uint16_t* D; int KTl; int g;
    if (t < 2048)      { W = W1;  D = F1;  KTl = 4; g = t; }
    else if (t < 6144) { W = Wf1; D = Ff1; KTl = 8; g = t - 2048; }
    else if (t < 8192) { W = W2;  D = F2;  KTl = 4; g = t - 6144; }
    else               { W = Wf2; D = Ff2; KTl = 8; g = t - 8192; }
    int c = g >> 6, l = g & 63;
    int tt = c / KTl, kk = c - tt * KTl;
    int m = l & 15, q = l >> 4;
    int n  = tt * 16 + m;
    int k0 = kk * 32 + q * 8;
    bf16x8 a;
#pragma unroll
    for (int j = 0; j < 8; j++) a[j] = (short)f2bf(W[(size_t)(k0 + j) * 128 + n]);
    *(bf16x8*)(D + (size_t)g * 8) = a;
  }
  if (blockIdx.x == 0) {
    int i = threadIdx.x;
    for (int j = i; j < 512; j += 256) {
      const float* src = (j < 128) ? b1 : (j < 256) ? bf1 : (j < 384) ? b2 : bf2;
      fb[j] = src[j & 127];
    }
    fgb[i] = (i < 128) ? gam[i] : bet[i & 127];
  }
}

// ---------- layer GEMM (K=128): D = relu(A @ W + b), bf16 out ----------
// 32-row blocks, 4 waves; wave = 32 rows x 2 col-tiles; B-fragments loaded
// once per tile and reused for both 16-row groups (halves weight traffic).
// MODE 1: A = f32 features, convert in-reg, wave0 side-writes bf16 to XOUT.
// MODE 2: A = bf16 y; fused BN (scsh) + row-L2-normalize; wave0 writes x.
// Tail block (M%32==16): row-group 1 guarded off.
template<int MODE>
__global__ __launch_bounds__(256) void gemm_l(
    const void* __restrict__ Av, const uint16_t* __restrict__ Wf,
    const float* __restrict__ bias, const float* __restrict__ scsh,
    uint16_t* __restrict__ D, uint16_t* __restrict__ XOUT, int M)
{
  const int lane = threadIdx.x & 63;
  const int wv   = threadIdx.x >> 6;
  const int row0 = blockIdx.x * 32;
  if (row0 >= M) return;
  const int m = lane & 15, quad = lane >> 4;

  bf16x8 afr[2][4];
#pragma unroll
  for (int g = 0; g < 2; g++) {
    if (row0 + g * 16 >= M) break;          // wave-uniform guard (M%16==0)
    const int arow = row0 + g * 16 + m;
    if (MODE == 1) {
      const float* A = (const float*)Av;
#pragma unroll
      for (int kk = 0; kk < 4; kk++) {
        const float* p = A + (size_t)arow * 128 + kk * 32 + quad * 8;
        f32x4 f0 = *(const f32x4*)p;
        f32x4 f1 = *(const f32x4*)(p + 4);
        bf16x8 a;
        a[0] = (short)f2bf(f0[0]); a[1] = (short)f2bf(f0[1]);
        a[2] = (short)f2bf(f0[2]); a[3] = (short)f2bf(f0[3]);
        a[4] = (short)f2bf(f1[0]); a[5] = (short)f2bf(f1[1]);
        a[6] = (short)f2bf(f1[2]); a[7] = (short)f2bf(f1[3]);
        afr[g][kk] = a;
      }
    } else {
      const uint16_t* A = (const uint16_t*)Av;
      float xv[32];
      float ss = 0.f;
#pragma unroll
      for (int kk = 0; kk < 4; kk++) {
        const int k0 = kk * 32 + quad * 8;
        bf16x8 y8 = *(const bf16x8*)(A + (size_t)arow * 128 + k0);
        f32x4 sc0 = *(const f32x4*)(scsh + k0);
        f32x4 sc1 = *(const f32x4*)(scsh + k0 + 4);
        f32x4 sh0 = *(const f32x4*)(scsh + 128 + k0);
        f32x4 sh1 = *(const f32x4*)(scsh + 128 + k0 + 4);
#pragma unroll
        for (int j = 0; j < 4; j++) {
          float a = bf2f((uint16_t)y8[j])     * sc0[j] + sh0[j];
          float b = bf2f((uint16_t)y8[4 + j]) * sc1[j] + sh1[j];
          xv[kk * 8 + j] = a; xv[kk * 8 + 4 + j] = b;
          ss += a * a + b * b;
        }
      }
      ss += __shfl_xor(ss, 16); ss += __shfl_xor(ss, 32);   // full 128-col row
      float inv = 1.0f / (sqrtf(ss) + 1e-6f);
#pragma unroll
      for (int kk = 0; kk < 4; kk++) {
        bf16x8 a;
#pragma unroll
        for (int j = 0; j < 8; j++) a[j] = (short)f2bf(xv[kk * 8 + j] * inv);
        afr[g][kk] = a;
      }
    }
    if (wv == 0) {                          // side-write Xb / x
#pragma unroll
      for (int kk = 0; kk < 4; kk++)
        *(bf16x8*)(XOUT + (size_t)arow * 128 + kk * 32 + quad * 8) = afr[g][kk];
    }
  }

#pragma unroll
  for (int t2 = 0; t2 < 2; t2++) {
    const int tt = wv * 2 + t2;
    bf16x8 bfr[4];
#pragma unroll
    for (int kk = 0; kk < 4; kk++)
      bfr[kk] = *(const bf16x8*)(Wf + ((size_t)(tt * 4 + kk) * 64 + lane) * 8);
    const int col = tt * 16 + m;
    const float bv = bias[col];
#pragma unroll
    for (int g = 0; g < 2; g++) {
      if (row0 + g * 16 >= M) break;
      f32x4 acc = {0.f, 0.f, 0.f, 0.f};
#pragma unroll
      for (int kk = 0; kk < 4; kk++)
        acc = __builtin_amdgcn_mfma_f32_16x16x32_bf16(afr[g][kk], bfr[kk], acc, 0, 0, 0);
#pragma unroll
      for (int r = 0; r < 4; r++) {
        float v = fmaxf(acc[r] + bv, 0.f);
        D[(size_t)(row0 + g * 16 + quad * 4 + r) * 128 + col] = f2bf(v);
      }
    }
  }
}

// ---------- gather-fused GEMM (K=256): D = act([A0, maxgather(H,idx)] @ W + b)
// 32-row blocks, 4 waves; wave = 32 rows x 2 tiles (B reused across the two
// 16-row groups -> weight L1 traffic halved vs 16-row blocks).
// Stage A: wave gathers 8 rows in 2 passes of 4 (quad=row, m=16B chunk),
// 25 loads batched 8/8/9. u16-max valid: H post-ReLU bf16 (bit-monotone).
// Tail block (M%32==16): rows clamped in gather, row-group 1 guarded off.
template<bool STATS, int ODT>
__global__ __launch_bounds__(256) void gemm_g(
    const uint16_t* __restrict__ A0, const uint16_t* __restrict__ H,
    const int* __restrict__ idx, const uint16_t* __restrict__ Wf,
    const float* __restrict__ bias, void* __restrict__ Dv,
    float* __restrict__ shadow, int M)
{
  __shared__ __align__(16) uint16_t agg[32 * 136];   // 8704 B, 272B row stride
  const int lane = threadIdx.x & 63;
  const int wv   = threadIdx.x >> 6;
  const int row0 = blockIdx.x * 32;
  if (row0 >= M) return;
  const int m = lane & 15, quad = lane >> 4;

  // prefetch A0 fragments (independent of the gather, overlaps it)
  bf16x8 afr[2][8];
#pragma unroll
  for (int g = 0; g < 2; g++) {
    if (row0 + g * 16 >= M) break;
    const int arow = row0 + g * 16 + m;
#pragma unroll
    for (int kk = 0; kk < 4; kk++)
      afr[g][kk] = *(const bf16x8*)(A0 + (size_t)arow * 128 + kk * 32 + quad * 8);
  }

  // ---- stage A: gather-max, 8 rows/wave in 2 passes ----
#pragma unroll
  for (int p = 0; p < 2; p++) {
    const int lr = wv * 8 + p * 4 + quad;   // local row 0..31
    int rw = row0 + lr;
    if (rw >= M) rw = M - 1;                // tail clamp (result unread)
    const int* ir = idx + (size_t)rw * 25;
    u16x8 mx = {0, 0, 0, 0, 0, 0, 0, 0};
#pragma unroll
    for (int b = 0; b < 3; b++) {           // 8 + 8 + 9 = 25
      const int cnt = (b == 2) ? 9 : 8;
      u16x8 v[9];
#pragma unroll
      for (int e = 0; e < 9; e++) {
        if (e < cnt) {
          uint32_t j = (uint32_t)ir[b * 8 + e];
          if (j >= (uint32_t)M) j = 0;      // safety clamp
          v[e] = *(const u16x8*)(H + (size_t)j * 128 + m * 8);
        }
      }
#pragma unroll
      for (int e = 0; e < 9; e++) {
        if (e < cnt) {
#pragma unroll
          for (int x = 0; x < 8; x++) mx[x] = (v[e][x] > mx[x]) ? v[e][x] : mx[x];
        }
      }
    }
    *(u16x8*)(&agg[lr * 136 + m * 8]) = mx;
  }
  __syncthreads();

#pragma unroll
  for (int g = 0; g < 2; g++) {
    if (row0 + g * 16 >= M) break;
#pragma unroll
    for (int kk = 0; kk < 4; kk++)
      afr[g][4 + kk] = *(const bf16x8*)(&agg[(g * 16 + m) * 136 + kk * 32 + quad * 8]);
  }

#pragma unroll
  for (int t2 = 0; t2 < 2; t2++) {
    const int tt = wv * 2 + t2;
    bf16x8 bfr[8];
#pragma unroll
    for (int kk = 0; kk < 8; kk++)
      bfr[kk] = *(const bf16x8*)(Wf + ((size_t)(tt * 8 + kk) * 64 + lane) * 8);
    const int col = tt * 16 + m;
    const float bv = bias[col];
    float s = 0.f, q = 0.f;
#pragma unroll
    for (int g = 0; g < 2; g++) {
      if (row0 + g * 16 >= M) break;
      f32x4 acc = {0.f, 0.f, 0.f, 0.f};
#pragma unroll
      for (int kk = 0; kk < 8; kk++)
        acc = __builtin_amdgcn_mfma_f32_16x16x32_bf16(afr[g][kk], bfr[kk], acc, 0, 0, 0);
#pragma unroll
      for (int r = 0; r < 4; r++) {
        float v = acc[r] + bv;
        if (STATS) v = fmaxf(v, 0.f);       // fc1 has ReLU; fc2 does not
        size_t oidx = (size_t)(row0 + g * 16 + quad * 4 + r) * 128 + col;
        if (ODT == 0) ((uint16_t*)Dv)[oidx] = f2bf(v);
        else          ((float*)Dv)[oidx] = v;
        if (STATS) { s += v; q += v * v; }
      }
    }
    if (STATS) {
      s += __shfl_xor(s, 16); s += __shfl_xor(s, 32);
      q += __shfl_xor(q, 16); q += __shfl_xor(q, 32);
      if (quad == 0) {
        float* slot = shadow + (size_t)(blockIdx.x & (NSHADOW - 1)) * 256;
        atomicAdd(&slot[col], s);
        atomicAdd(&slot[128 + col], q);
      }
    }
  }
}

// ---------- BN finalize: shadow slots -> [scale|shift] (1 block) ----------
__global__ __launch_bounds__(256) void bn_fin_k(
    const float* __restrict__ shadow, const float* __restrict__ fgb,
    float* __restrict__ scsh, int M)
{
  __shared__ float ps[256], pq[256];
  const int tid = threadIdx.x;
  const int col = tid & 127, part = tid >> 7;
  float s = 0.f, q = 0.f;
#pragma unroll 8
  for (int sl = part * 32; sl < part * 32 + 32; sl++) {
    s += shadow[sl * 256 + col];
    q += shadow[sl * 256 + 128 + col];
  }
  ps[tid] = s; pq[tid] = q;
  __syncthreads();
  if (tid < 128) {
    s = ps[tid] + ps[tid + 128];
    q = pq[tid] + pq[tid + 128];
    float invN = 1.0f / (float)M;
    float mean = s * invN;
    float var  = fmaxf(q * invN - mean * mean, 0.f);
    float g = fgb[tid] * rsqrtf(var + 1e-5f);
    scsh[tid] = g;
    scsh[128 + tid] = fgb[128 + tid] - mean * g;
  }
}

// ---------- launch ----------
extern "C" void kernel_launch(void* const* d_in, const int* in_sizes, int n_in,
                              void* d_out, int out_size, void* d_ws, size_t ws_size,
                              hipStream_t stream)
{
  const float* features = (const float*)d_in[0];
  const int*   idx1     = (const int*)d_in[1];
  const int*   idx2     = (const int*)d_in[2];
  const float* agg1_W   = (const float*)d_in[3];
  const float* agg1_b   = (const float*)d_in[4];
  const float* fc1_W    = (const float*)d_in[5];
  const float* fc1_b    = (const float*)d_in[6];
  const float* agg2_W   = (const float*)d_in[7];
  const float* agg2_b   = (const float*)d_in[8];
  const float* fc2_W    = (const float*)d_in[9];
  const float* fc2_b    = (const float*)d_in[10];
  const float* bn_g     = (const float*)d_in[11];
  const float* bn_b     = (const float*)d_in[12];

  const int N = in_sizes[0] / 128;          // 50000 (N % 16 == 0)

  // workspace carve-up (16B-aligned); ~64.3 MB
  char* w = (char*)d_ws;
  float* shadow = (float*)w; w += NSHADOW * 256 * 4;
  uint16_t* F1  = (uint16_t*)w; w += 128 * 128 * 2;   // frag-order weights
  uint16_t* Ff1 = (uint16_t*)w; w += 128 * 256 * 2;
  uint16_t* F2  = (uint16_t*)w; w += 128 * 128 * 2;
  uint16_t* Ff2 = (uint16_t*)w; w += 128 * 256 * 2;
  float* fb   = (float*)w; w += 512 * 4;    // [b1|bf1|b2|bf2]
  float* fgb  = (float*)w; w += 256 * 4;    // [gamma|beta]
  float* scsh = (float*)w; w += 256 * 4;    // BN [scale|shift]
  size_t NB = (size_t)N * 128 * 2;
  uint16_t* Xb = (uint16_t*)w; w += NB;     // features bf16
  uint16_t* h1 = (uint16_t*)w; w += NB;
  uint16_t* yb = (uint16_t*)w; w += NB;
  uint16_t* xb = (uint16_t*)w; w += NB;     // normalized layer-1 output
  uint16_t* h2 = (uint16_t*)w; w += NB;

  const int tb = (N + 31) / 32;             // 1563 (last block: 16 rows)

  // 1. weights -> fragment order; biases; zero shadow
  prep_k<<<48, 256, 0, stream>>>(agg1_W, fc1_W, agg2_W, fc2_W,
      agg1_b, fc1_b, agg2_b, fc2_b, bn_g, bn_b,
      F1, Ff1, F2, Ff2, fb, fgb, shadow);
  // 2. h1 = relu(X @ W1 + b1); side-write Xb (bf16 features)
  gemm_l<1><<<tb, 256, 0, stream>>>(features, F1, fb + 0, nullptr, h1, Xb, N);
  // 3. y = relu([Xb, maxgather(h1,idx1)] @ fc1 + b) + BN stats
  gemm_g<true, 0><<<tb, 256, 0, stream>>>(Xb, h1, idx1, Ff1, fb + 128, yb, shadow, N);
  // 4. BN finalize
  bn_fin_k<<<1, 256, 0, stream>>>(shadow, fgb, scsh, N);
  // 5. h2 = relu(L2norm(BN(y)) @ W2 + b2); side-write x
  gemm_l<2><<<tb, 256, 0, stream>>>(yb, F2, fb + 256, scsh, h2, xb, N);
  // 6. out = [x, maxgather(h2,idx2)] @ fc2 + b -> d_out (f32)
  gemm_g<false, 1><<<tb, 256, 0, stream>>>(xb, h2, idx2, Ff2, fb + 384, d_out, nullptr, N);

  (void)n_in; (void)out_size; (void)ws_size;
}